// Round 5
// baseline (660.532 us; speedup 1.0000x reference)
//
#include <hip/hip_runtime.h>

#define DD 256
#define HWN 1024
#define NN 32768
#define KK 1024
#define MARGIN 1e-4f
#define FLAGBIT (1 << 30)

// f32-element offsets into d_out (out_size = 16809984 floats):
#define ZQ_OFF   0          // z_q   [32,256,32,32]
#define IDX_OFF  8388608    // idx   [32768]
#define LOSS_OFF 8421376    // loss  [32,32,32,256] (NHWC)

// ws layout:
// [0, 4096)         float e2[1024]    (numpy-pairwise-exact f32 ||e_k||^2)
// [4096, 135168)    float z2[32768]   (numpy-pairwise-exact f32 ||z_n||^2)
// [135168, 266240)  int   bestIdx[32768]  (bit30 = near-tie flag)

// ---- numpy pairwise sum emulation (n=256, contiguous logical order) ----
// numpy: n=256 -> pairwise(0,128) + pairwise(128,128); each 128-block uses
// 8 accumulators r[j]=a[j]; r[j]+=a[i+j] for i=8..120; combine
// ((r0+r1)+(r2+r3))+((r4+r5)+(r6+r7)). All single-rounded f32 ops (no FMA).

// ---------------- e2[k]: numpy-exact f32 codebook norms ----------------
__global__ __launch_bounds__(64) void k_e2(const float* __restrict__ E,
                                           float* __restrict__ e2) {
    int k = (blockIdx.x << 6) + threadIdx.x;   // one code row per thread
    const float* row = E + (size_t)k * DD;
    float half[2];
#pragma unroll
    for (int h = 0; h < 2; ++h) {
        const float* a = row + (h << 7);
        float r[8];
#pragma unroll
        for (int j = 0; j < 8; ++j) r[j] = __fmul_rn(a[j], a[j]);
        for (int i = 8; i < 128; i += 8) {
#pragma unroll
            for (int j = 0; j < 8; ++j) {
                float x = a[i + j];
                r[j] = __fadd_rn(r[j], __fmul_rn(x, x));
            }
        }
        half[h] = __fadd_rn(__fadd_rn(__fadd_rn(r[0], r[1]), __fadd_rn(r[2], r[3])),
                            __fadd_rn(__fadd_rn(r[4], r[5]), __fadd_rn(r[6], r[7])));
    }
    e2[k] = __fadd_rn(half[0], half[1]);
}

// ---------------- z2[n]: numpy-exact f32 z-row norms (strided reads) ----------------
__global__ __launch_bounds__(256) void k_z2(const float* __restrict__ Z,
                                            float* __restrict__ z2) {
    int n = (blockIdx.x << 8) + threadIdx.x;   // one spatial row per thread
    int b = n >> 10, hw = n & 1023;
    const float* base = Z + (size_t)(b << 8) * HWN + hw;   // element d at base[d*HWN]
    float half[2];
#pragma unroll
    for (int h = 0; h < 2; ++h) {
        const float* a = base + (size_t)(h << 7) * HWN;
        float r[8];
#pragma unroll
        for (int j = 0; j < 8; ++j) {
            float x = a[(size_t)j * HWN];
            r[j] = __fmul_rn(x, x);
        }
        for (int i = 8; i < 128; i += 8) {
#pragma unroll
            for (int j = 0; j < 8; ++j) {
                float x = a[(size_t)(i + j) * HWN];
                r[j] = __fadd_rn(r[j], __fmul_rn(x, x));
            }
        }
        half[h] = __fadd_rn(__fadd_rn(__fadd_rn(r[0], r[1]), __fadd_rn(r[2], r[3])),
                            __fadd_rn(__fadd_rn(r[4], r[5]), __fadd_rn(r[6], r[7])));
    }
    z2[n] = __fadd_rn(half[0], half[1]);
}

// ---------------- fp32 distance pass + near-tie flagging + fused loss ----------------
#define UPD(m1, m2, i1, s, k)                            \
    do {                                                 \
        if ((s) < (m1)) { m2 = m1; m1 = (s); i1 = (k); } \
        else if ((s) < (m2)) { m2 = (s); }               \
    } while (0)

__global__ __launch_bounds__(256) void k_dist(const float* __restrict__ Z,
                                              const float* __restrict__ E,
                                              const float* __restrict__ e2,
                                              int* __restrict__ bestIdx,
                                              float* __restrict__ out) {
    __shared__ float zs[32][DD + 4];   // 33280 B
    __shared__ float es[16][DD + 4];   // 16640 B
    __shared__ float sc[768];          //  3072 B
    __shared__ int   fi[32];           //   128 B  -> 53120 B < 64 KiB

    const int th = threadIdx.x;
    const int n0 = blockIdx.x << 5;    // 32 rows per block
    const int b = n0 >> 10;
    const int hw0 = n0 & 1023;

    for (int j = 0; j < 32; ++j) {
        int li = (j << 8) + th;
        int d = li >> 5;
        int r = li & 31;
        zs[r][d] = Z[(size_t)((b << 8) + d) * HWN + hw0 + r];
    }

    const int dg = th >> 7;
    const int tc = th & 7;
    const int tr = (th >> 3) & 15;
    const int dbase = dg << 7;

    float m1a = __builtin_inff(), m2a = __builtin_inff();
    float m1b = __builtin_inff(), m2b = __builtin_inff();
    int i1a = 0, i1b = 0;

    for (int kt = 0; kt < 64; ++kt) {
        const int k0 = kt << 4;
        __syncthreads();
        for (int j = 0; j < 4; ++j) {
            int fi2 = (j << 8) + th;
            int c = fi2 >> 6;
            int d4 = (fi2 & 63) << 2;
            *reinterpret_cast<float4*>(&es[c][d4]) =
                *reinterpret_cast<const float4*>(&E[(size_t)(k0 + c) * DD + d4]);
        }
        __syncthreads();

        float a00 = 0.f, a01 = 0.f, a10 = 0.f, a11 = 0.f;
#pragma unroll 4
        for (int dq = 0; dq < 128; dq += 4) {
            const int d = dbase + dq;
            float4 z0 = *reinterpret_cast<const float4*>(&zs[tr][d]);
            float4 z1 = *reinterpret_cast<const float4*>(&zs[tr + 16][d]);
            float4 e0 = *reinterpret_cast<const float4*>(&es[tc][d]);
            float4 e1 = *reinterpret_cast<const float4*>(&es[tc + 8][d]);
            a00 = fmaf(z0.x, e0.x, a00); a00 = fmaf(z0.y, e0.y, a00);
            a00 = fmaf(z0.z, e0.z, a00); a00 = fmaf(z0.w, e0.w, a00);
            a01 = fmaf(z0.x, e1.x, a01); a01 = fmaf(z0.y, e1.y, a01);
            a01 = fmaf(z0.z, e1.z, a01); a01 = fmaf(z0.w, e1.w, a01);
            a10 = fmaf(z1.x, e0.x, a10); a10 = fmaf(z1.y, e0.y, a10);
            a10 = fmaf(z1.z, e0.z, a10); a10 = fmaf(z1.w, e0.w, a10);
            a11 = fmaf(z1.x, e1.x, a11); a11 = fmaf(z1.y, e1.y, a11);
            a11 = fmaf(z1.z, e1.z, a11); a11 = fmaf(z1.w, e1.w, a11);
        }

        if (dg == 1) {
            int s4 = ((tr << 3) + tc) << 2;
            sc[s4] = a00; sc[s4 + 1] = a01; sc[s4 + 2] = a10; sc[s4 + 3] = a11;
        }
        __syncthreads();
        if (dg == 0) {
            int s4 = ((tr << 3) + tc) << 2;
            a00 += sc[s4]; a01 += sc[s4 + 1]; a10 += sc[s4 + 2]; a11 += sc[s4 + 3];
            const int ca = k0 + tc;
            const int cb = k0 + tc + 8;
            const float ena = e2[ca];
            const float enb = e2[cb];
            float s;
            s = fmaf(-2.f, a00, ena); UPD(m1a, m2a, i1a, s, ca);
            s = fmaf(-2.f, a01, enb); UPD(m1a, m2a, i1a, s, cb);
            s = fmaf(-2.f, a10, ena); UPD(m1b, m2b, i1b, s, ca);
            s = fmaf(-2.f, a11, enb); UPD(m1b, m2b, i1b, s, cb);
        }
    }

    __syncthreads();
    if (dg == 0) {
        int base = ((tr << 3) + tc) * 3;
        sc[base] = m1a; sc[base + 1] = m2a; sc[base + 2] = (float)i1a;
        base = (((tr + 16) << 3) + tc) * 3;
        sc[base] = m1b; sc[base + 1] = m2b; sc[base + 2] = (float)i1b;
    }
    __syncthreads();
    if (th < 32) {
        float M1 = __builtin_inff(), M2 = __builtin_inff(), I = 3.4e38f;
        for (int t = 0; t < 8; ++t) {
            int base = ((th << 3) + t) * 3;
            float v1 = sc[base], v2 = sc[base + 1], vi = sc[base + 2];
            if (v1 < M1)       { M2 = fminf(M1, v2); M1 = v1; I = vi; }
            else if (v1 == M1) { I = fminf(I, vi); M2 = fminf(M2, v1); M2 = fminf(M2, v2); }
            else               { M2 = fminf(M2, v1); }
        }
        int idx = (int)I;
        fi[th] = idx;
        bestIdx[n0 + th] = (M2 - M1 < MARGIN) ? (idx | FLAGBIT) : idx;
    }
    __syncthreads();

    // fused loss (NHWC, coalesced float4); k_refine rewrites flagged rows
    const int l2 = th & 63;
    const int g2 = th >> 6;
    for (int r = g2; r < 32; r += 4) {
        int idx = fi[r];
        float4 e4 = *reinterpret_cast<const float4*>(&E[(size_t)idx * DD + (l2 << 2)]);
        float4 z4 = *reinterpret_cast<const float4*>(&zs[r][l2 << 2]);
        float4 o;
        o.x = (e4.x - z4.x) * (e4.x - z4.x);
        o.y = (e4.y - z4.y) * (e4.y - z4.y);
        o.z = (e4.z - z4.z) * (e4.z - z4.z);
        o.w = (e4.w - z4.w) * (e4.w - z4.w);
        *reinterpret_cast<float4*>(&out[LOSS_OFF + (size_t)(n0 + r) * DD + (l2 << 2)]) = o;
    }
}

// -------- np-f32-emulating re-argmin for flagged rows (+loss rewrite) --------
// g_k = fl32( fl32(z2 + e2_k) - fl32(2 * fl32(dot_k)) ), dot_k exact in f64.
// argmin with lowest-index tie-break == np.argmin semantics.
__global__ __launch_bounds__(64) void k_refine(const float* __restrict__ Z,
                                               const float* __restrict__ E,
                                               const float* __restrict__ e2,
                                               const float* __restrict__ z2,
                                               int* __restrict__ bestIdx,
                                               float* __restrict__ out) {
    __shared__ float zr[DD];
    const int l = threadIdx.x;
    for (int i = 0; i < 16; ++i) {
        int n = (blockIdx.x << 4) + i;
        if (!(bestIdx[n] & FLAGBIT)) continue;   // uniform (single-wave block)
        int b = n >> 10, hw = n & 1023;
        __syncthreads();
#pragma unroll
        for (int j = 0; j < 4; ++j)
            zr[(l << 2) + j] = Z[(size_t)((b << 8) + (l << 2) + j) * HWN + hw];
        __syncthreads();
        const float z2v = z2[n];
        float gbest = __builtin_inff();
        int bi = KK;
        for (int kk = 0; kk < 16; ++kk) {
            int k = (kk << 6) + l;               // ascending per lane
            double dot = 0.0;
            for (int d = 0; d < DD; d += 4) {
                float4 e4 = *reinterpret_cast<const float4*>(&E[(size_t)k * DD + d]);
                dot += (double)e4.x * zr[d]     + (double)e4.y * zr[d + 1]
                     + (double)e4.z * zr[d + 2] + (double)e4.w * zr[d + 3];
            }
            float c = (float)dot;                // np's f32 cross (to sgemm noise)
            float t = __fmul_rn(2.0f, c);
            float g = __fsub_rn(__fadd_rn(z2v, e2[k]), t);
            if (g < gbest) { gbest = g; bi = k; }   // first (lowest k) wins ties
        }
#pragma unroll
        for (int off = 32; off > 0; off >>= 1) {
            float og = __shfl_down(gbest, off);
            int oi = __shfl_down(bi, off);
            if (og < gbest || (og == gbest && oi < bi)) { gbest = og; bi = oi; }
        }
        int bi0 = __shfl(bi, 0);
        if (l == 0) bestIdx[n] = bi0;
        float4 e4 = *reinterpret_cast<const float4*>(&E[(size_t)bi0 * DD + (l << 2)]);
        float z0 = zr[(l << 2)], z1 = zr[(l << 2) + 1],
              z2a = zr[(l << 2) + 2], z3 = zr[(l << 2) + 3];
        float4 o;
        o.x = (e4.x - z0) * (e4.x - z0);
        o.y = (e4.y - z1) * (e4.y - z1);
        o.z = (e4.z - z2a) * (e4.z - z2a);
        o.w = (e4.w - z3) * (e4.w - z3);
        *reinterpret_cast<float4*>(&out[LOSS_OFF + (size_t)n * DD + (l << 2)]) = o;
    }
}

// ---------------- z_q (NCHW, coalesced) + indices, f32 ----------------
__global__ __launch_bounds__(256) void k_out(const float* __restrict__ E,
                                             const int* __restrict__ bestIdx,
                                             float* __restrict__ out) {
    const int blk = blockIdx.x;        // 512 blocks
    const int b = blk >> 4;
    const int hw0 = (blk & 15) << 6;
    const int th = threadIdx.x;
    __shared__ int idxs[64];
    if (th < 64) {
        int n = (b << 10) + hw0 + th;
        int id = bestIdx[n] & 1023;
        idxs[th] = id;
        out[IDX_OFF + n] = (float)id;
    }
    __syncthreads();
    const int hw_l = th & 63;
    const int di = th >> 6;
    const int hw = hw0 + hw_l;
    const int eRow = idxs[hw_l] << 8;
    for (int d0 = 0; d0 < DD; d0 += 4) {
        int d = d0 + di;
        out[ZQ_OFF + (size_t)((b << 8) + d) * HWN + hw] = E[eRow + d];
    }
}

extern "C" void kernel_launch(void* const* d_in, const int* in_sizes, int n_in,
                              void* d_out, int out_size, void* d_ws, size_t ws_size,
                              hipStream_t stream) {
    const float* Z = (const float*)d_in[0];           // [32,256,32,32] f32
    const float* E = (const float*)d_in[1];           // [1024,256] f32
    float* out = (float*)d_out;
    char* ws = (char*)d_ws;
    float* e2 = (float*)ws;
    float* z2 = (float*)(ws + 4096);
    int* bestIdx = (int*)(ws + 135168);

    k_e2<<<KK / 64, 64, 0, stream>>>(E, e2);
    k_z2<<<NN / 256, 256, 0, stream>>>(Z, z2);
    k_dist<<<NN / 32, 256, 0, stream>>>(Z, E, e2, bestIdx, out);
    k_refine<<<NN / 16, 64, 0, stream>>>(Z, E, e2, z2, bestIdx, out);
    k_out<<<512, 256, 0, stream>>>(E, bestIdx, out);
}

// Round 6
// 640.325 us; speedup vs baseline: 1.0316x; 1.0316x over previous
//
#include <hip/hip_runtime.h>

#define DD 256
#define HWN 1024
#define NN 32768
#define KK 1024
#define MARGIN 1e-4f
#define FLAGBIT (1 << 30)

// f32-element offsets into d_out (out_size = 16809984 floats):
#define ZQ_OFF   0          // z_q   [32,256,32,32]
#define IDX_OFF  8388608    // idx   [32768]
#define LOSS_OFF 8421376    // loss  [32,32,32,256] (NHWC)

// ws layout:
// [0, 4096)         float e2[1024]    (numpy-pairwise-exact f32 ||e_k||^2)
// [4096, 135168)    float z2[32768]   (numpy-pairwise-exact f32 ||z_n||^2)
// [135168, 266240)  int   bestIdx[32768]  (bit30 = near-tie flag)

// ---------------- e2[k]: numpy-exact f32 codebook norms ----------------
__global__ __launch_bounds__(64) void k_e2(const float* __restrict__ E,
                                           float* __restrict__ e2) {
    int k = (blockIdx.x << 6) + threadIdx.x;
    const float* row = E + (size_t)k * DD;
    float half[2];
#pragma unroll
    for (int h = 0; h < 2; ++h) {
        const float* a = row + (h << 7);
        float r[8];
#pragma unroll
        for (int j = 0; j < 8; ++j) r[j] = __fmul_rn(a[j], a[j]);
        for (int i = 8; i < 128; i += 8) {
#pragma unroll
            for (int j = 0; j < 8; ++j) {
                float x = a[i + j];
                r[j] = __fadd_rn(r[j], __fmul_rn(x, x));
            }
        }
        half[h] = __fadd_rn(__fadd_rn(__fadd_rn(r[0], r[1]), __fadd_rn(r[2], r[3])),
                            __fadd_rn(__fadd_rn(r[4], r[5]), __fadd_rn(r[6], r[7])));
    }
    e2[k] = __fadd_rn(half[0], half[1]);
}

// ---------------- z2[n]: numpy-exact f32 z-row norms ----------------
__global__ __launch_bounds__(256) void k_z2(const float* __restrict__ Z,
                                            float* __restrict__ z2) {
    int n = (blockIdx.x << 8) + threadIdx.x;
    int b = n >> 10, hw = n & 1023;
    const float* base = Z + (size_t)(b << 8) * HWN + hw;
    float half[2];
#pragma unroll
    for (int h = 0; h < 2; ++h) {
        const float* a = base + (size_t)(h << 7) * HWN;
        float r[8];
#pragma unroll
        for (int j = 0; j < 8; ++j) {
            float x = a[(size_t)j * HWN];
            r[j] = __fmul_rn(x, x);
        }
        for (int i = 8; i < 128; i += 8) {
#pragma unroll
            for (int j = 0; j < 8; ++j) {
                float x = a[(size_t)(i + j) * HWN];
                r[j] = __fadd_rn(r[j], __fmul_rn(x, x));
            }
        }
        half[h] = __fadd_rn(__fadd_rn(__fadd_rn(r[0], r[1]), __fadd_rn(r[2], r[3])),
                            __fadd_rn(__fadd_rn(r[4], r[5]), __fadd_rn(r[6], r[7])));
    }
    z2[n] = __fadd_rn(half[0], half[1]);
}

// ---- fp32 distance pass, 64-row x 128-code tile, 4x8 register tile ----
#define UPD(m1, m2, i1, s, k)                            \
    do {                                                 \
        if ((s) < (m1)) { m2 = m1; m1 = (s); i1 = (k); } \
        else if ((s) < (m2)) { m2 = (s); }               \
    } while (0)

#define FMAJ(j, EV, C)                                   \
    acc[0][j] = fmaf(z4.x, EV.C, acc[0][j]);             \
    acc[1][j] = fmaf(z4.y, EV.C, acc[1][j]);             \
    acc[2][j] = fmaf(z4.z, EV.C, acc[2][j]);             \
    acc[3][j] = fmaf(z4.w, EV.C, acc[3][j]);

#define UROUND(u, C)                                                          \
    {                                                                         \
        float4 z4 = *reinterpret_cast<const float4*>(&zs[dq + u][ty4]);       \
        FMAJ(0, e0, C) FMAJ(1, e1, C) FMAJ(2, e2v, C) FMAJ(3, e3, C)          \
        FMAJ(4, e4, C) FMAJ(5, e5, C) FMAJ(6, e6, C) FMAJ(7, e7, C)           \
    }

__global__ __launch_bounds__(256, 3) void k_dist(const float* __restrict__ Z,
                                                 const float* __restrict__ E,
                                                 const float* __restrict__ e2,
                                                 int* __restrict__ bestIdx) {
    __shared__ float zs[64][68];       // 17408 B, zs[d][row] (matches Z layout)
    __shared__ float es[128][68];      // 34816 B, es[code][d] (matches E layout)
    // total 52224 B; es reused as reduction scratch at the end

    const int th = threadIdx.x;
    const int n0 = blockIdx.x << 6;    // 64 rows per block
    const int b = n0 >> 10;
    const int hw0 = n0 & 1023;

    const int tx = th & 15;            // code group: codes tx + 16j, j=0..7
    const int ty = th >> 4;            // row group: rows 4*ty .. 4*ty+3
    const int ty4 = ty << 2;

    float m1[4], m2[4];
    int idx[4];
#pragma unroll
    for (int i = 0; i < 4; ++i) { m1[i] = __builtin_inff(); m2[i] = __builtin_inff(); idx[i] = 0; }

    for (int ct = 0; ct < 8; ++ct) {   // 8 code tiles of 128
        float acc[4][8];
#pragma unroll
        for (int i = 0; i < 4; ++i)
#pragma unroll
            for (int j = 0; j < 8; ++j) acc[i][j] = 0.f;

        for (int dc = 0; dc < 4; ++dc) {   // 4 d-chunks of 64
            __syncthreads();
            // stage zs[dd][r]: 4096 floats, b128 both sides, no transpose
#pragma unroll
            for (int j = 0; j < 4; ++j) {
                int i4 = (j << 8) + th;        // 0..1023 float4 slots
                int dd = i4 >> 4;              // 0..63
                int rr = (i4 & 15) << 2;       // 0..60
                *reinterpret_cast<float4*>(&zs[dd][rr]) =
                    *reinterpret_cast<const float4*>(
                        &Z[(size_t)((b << 8) + (dc << 6) + dd) * HWN + hw0 + rr]);
            }
            // stage es[c][d]: 8192 floats
#pragma unroll
            for (int j = 0; j < 8; ++j) {
                int i4 = (j << 8) + th;        // 0..2047
                int c = i4 >> 4;               // 0..127
                int d4 = (i4 & 15) << 2;       // 0..60
                *reinterpret_cast<float4*>(&es[c][d4]) =
                    *reinterpret_cast<const float4*>(
                        &E[(size_t)((ct << 7) + c) * DD + (dc << 6) + d4]);
            }
            __syncthreads();

#pragma unroll
            for (int dq = 0; dq < 64; dq += 4) {
                float4 e0 = *reinterpret_cast<const float4*>(&es[tx][dq]);
                float4 e1 = *reinterpret_cast<const float4*>(&es[tx + 16][dq]);
                float4 e2v = *reinterpret_cast<const float4*>(&es[tx + 32][dq]);
                float4 e3 = *reinterpret_cast<const float4*>(&es[tx + 48][dq]);
                float4 e4 = *reinterpret_cast<const float4*>(&es[tx + 64][dq]);
                float4 e5 = *reinterpret_cast<const float4*>(&es[tx + 80][dq]);
                float4 e6 = *reinterpret_cast<const float4*>(&es[tx + 96][dq]);
                float4 e7 = *reinterpret_cast<const float4*>(&es[tx + 112][dq]);
                UROUND(0, x)
                UROUND(1, y)
                UROUND(2, z)
                UROUND(3, w)
            }
        }

        // distances + min-tracking for this code tile
#pragma unroll
        for (int j = 0; j < 8; ++j) {
            int c = (ct << 7) + tx + (j << 4);
            float en = e2[c];
#pragma unroll
            for (int i = 0; i < 4; ++i) {
                float s = fmaf(-2.f, acc[i][j], en);
                UPD(m1[i], m2[i], idx[i], s, c);
            }
        }
    }

    // cross-tx reduction: 16 partials per row, via es scratch
    __syncthreads();
    float* red = &es[0][0];            // 64*16*3 = 3072 floats
#pragma unroll
    for (int i = 0; i < 4; ++i) {
        int r = ty4 + i;
        int base = ((r << 4) + tx) * 3;
        red[base] = m1[i]; red[base + 1] = m2[i]; red[base + 2] = (float)idx[i];
    }
    __syncthreads();
    if (th < 64) {
        float M1 = __builtin_inff(), M2 = __builtin_inff(), I = 3.4e38f;
        for (int t = 0; t < 16; ++t) {
            int base = ((th << 4) + t) * 3;
            float v1 = red[base], v2 = red[base + 1], vi = red[base + 2];
            if (v1 < M1)       { M2 = fminf(M1, v2); M1 = v1; I = vi; }
            else if (v1 == M1) { I = fminf(I, vi); M2 = fminf(M2, v1); M2 = fminf(M2, v2); }
            else               { M2 = fminf(M2, v1); }
        }
        int id = (int)I;
        bestIdx[n0 + th] = (M2 - M1 < MARGIN) ? (id | FLAGBIT) : id;
    }
}

// -------- np-f32-emulating re-argmin for flagged rows --------
// g_k = fl32( fl32(z2 + e2_k) - fl32(2 * fl32(dot_k)) ), dot_k exact in f64.
__global__ __launch_bounds__(64) void k_refine(const float* __restrict__ Z,
                                               const float* __restrict__ E,
                                               const float* __restrict__ e2,
                                               const float* __restrict__ z2,
                                               int* __restrict__ bestIdx) {
    __shared__ float zr[DD];
    const int l = threadIdx.x;
    for (int i = 0; i < 16; ++i) {
        int n = (blockIdx.x << 4) + i;
        if (!(bestIdx[n] & FLAGBIT)) continue;   // uniform (single-wave block)
        int b = n >> 10, hw = n & 1023;
        __syncthreads();
#pragma unroll
        for (int j = 0; j < 4; ++j)
            zr[(l << 2) + j] = Z[(size_t)((b << 8) + (l << 2) + j) * HWN + hw];
        __syncthreads();
        const float z2v = z2[n];
        float gbest = __builtin_inff();
        int bi = KK;
        for (int kk = 0; kk < 16; ++kk) {
            int k = (kk << 6) + l;
            double dot = 0.0;
            for (int d = 0; d < DD; d += 4) {
                float4 e4 = *reinterpret_cast<const float4*>(&E[(size_t)k * DD + d]);
                dot += (double)e4.x * zr[d]     + (double)e4.y * zr[d + 1]
                     + (double)e4.z * zr[d + 2] + (double)e4.w * zr[d + 3];
            }
            float c = (float)dot;
            float t = __fmul_rn(2.0f, c);
            float g = __fsub_rn(__fadd_rn(z2v, e2[k]), t);
            if (g < gbest) { gbest = g; bi = k; }
        }
#pragma unroll
        for (int off = 32; off > 0; off >>= 1) {
            float og = __shfl_down(gbest, off);
            int oi = __shfl_down(bi, off);
            if (og < gbest || (og == gbest && oi < bi)) { gbest = og; bi = oi; }
        }
        if (l == 0) bestIdx[n] = bi;   // clears flag
    }
}

// -------- outputs: idx, loss (NHWC), z_q (NCHW), all f32, final indices --------
__global__ __launch_bounds__(256) void k_out(const float* __restrict__ Z,
                                             const float* __restrict__ E,
                                             const int* __restrict__ bestIdx,
                                             float* __restrict__ out) {
    __shared__ float zc[64][68];       // 17408 B, zc[row][d-chunk]
    __shared__ int idxs[64];
    const int th = threadIdx.x;
    const int n0 = blockIdx.x << 6;    // 64 rows per block (512 blocks)
    const int b = n0 >> 10;
    const int hw0 = n0 & 1023;

    if (th < 64) {
        int id = bestIdx[n0 + th] & 1023;
        idxs[th] = id;
        out[IDX_OFF + n0 + th] = (float)id;
    }
    __syncthreads();

    for (int dc = 0; dc < 4; ++dc) {
        __syncthreads();               // protect zc before overwrite
        // stage z chunk (transposing: coalesced reads, strided LDS writes)
#pragma unroll
        for (int j = 0; j < 16; ++j) {
            int li = (j << 8) + th;    // 0..4095
            int dd = li >> 6;
            int r = li & 63;
            zc[r][dd] = Z[(size_t)((b << 8) + (dc << 6) + dd) * HWN + hw0 + r];
        }
        __syncthreads();
        // loss (NHWC), float4 coalesced
#pragma unroll
        for (int j = 0; j < 4; ++j) {
            int i4 = (j << 8) + th;    // 0..1023
            int r = i4 >> 4;
            int f = (i4 & 15) << 2;
            float4 e4 = *reinterpret_cast<const float4*>(
                &E[(size_t)idxs[r] * DD + (dc << 6) + f]);
            float4 z4 = *reinterpret_cast<const float4*>(&zc[r][f]);
            float4 o;
            o.x = (e4.x - z4.x) * (e4.x - z4.x);
            o.y = (e4.y - z4.y) * (e4.y - z4.y);
            o.z = (e4.z - z4.z) * (e4.z - z4.z);
            o.w = (e4.w - z4.w) * (e4.w - z4.w);
            *reinterpret_cast<float4*>(
                &out[LOSS_OFF + (size_t)(n0 + r) * DD + (dc << 6) + f]) = o;
        }
        // z_q (NCHW), coalesced along hw
#pragma unroll
        for (int j = 0; j < 16; ++j) {
            int li = (j << 8) + th;
            int dd = li >> 6;
            int r = li & 63;
            out[ZQ_OFF + (size_t)((b << 8) + (dc << 6) + dd) * HWN + hw0 + r] =
                E[(size_t)idxs[r] * DD + (dc << 6) + dd];
        }
    }
}

extern "C" void kernel_launch(void* const* d_in, const int* in_sizes, int n_in,
                              void* d_out, int out_size, void* d_ws, size_t ws_size,
                              hipStream_t stream) {
    const float* Z = (const float*)d_in[0];           // [32,256,32,32] f32
    const float* E = (const float*)d_in[1];           // [1024,256] f32
    float* out = (float*)d_out;
    char* ws = (char*)d_ws;
    float* e2 = (float*)ws;
    float* z2 = (float*)(ws + 4096);
    int* bestIdx = (int*)(ws + 135168);

    k_e2<<<KK / 64, 64, 0, stream>>>(E, e2);
    k_z2<<<NN / 256, 256, 0, stream>>>(Z, z2);
    k_dist<<<NN / 64, 256, 0, stream>>>(Z, E, e2, bestIdx);
    k_refine<<<NN / 16, 64, 0, stream>>>(Z, E, e2, z2, bestIdx);
    k_out<<<NN / 64, 256, 0, stream>>>(Z, E, bestIdx, out);
}

// Round 7
// 423.933 us; speedup vs baseline: 1.5581x; 1.5104x over previous
//
#include <hip/hip_runtime.h>

#define DD 256
#define HWN 1024
#define NN 32768
#define KK 1024
#define MARGIN 1e-4f
#define FLAGBIT (1 << 30)

// f32-element offsets into d_out (out_size = 16809984 floats):
#define ZQ_OFF   0          // z_q   [32,256,32,32]
#define IDX_OFF  8388608    // idx   [32768]
#define LOSS_OFF 8421376    // loss  [32,32,32,256] (NHWC)

// ws layout (MFMA path needs 38,014,976 B; else fp32 fallback):
// [0, 4096)            float e2[1024]
// [4096, 135168)       float z2[32768]
// [135168, 266240)     int   bestIdx[32768]  (bit30 = near-tie flag)
// [266240, 3411968)    float part[32768][8][3]  (per-code-slice m1,m2,idx)
// [3411968, 3936256)   ushort Eh[1024][256]
// [3936256, 4460544)   ushort El[1024][256]
// [4460544, 21237760)  ushort Zh[32768][256]
// [21237760, 38014976) ushort Zl[32768][256]
#define WS_NEED 38014976

typedef __attribute__((ext_vector_type(8))) short bf16x8;
typedef __attribute__((ext_vector_type(4))) float f32x4;

__device__ __forceinline__ ushort f2b_rne(float x) {
    union { float f; unsigned u; } v; v.f = x;
    unsigned r = v.u + 0x7fffu + ((v.u >> 16) & 1u);
    return (ushort)(r >> 16);
}
__device__ __forceinline__ float b2f(ushort u) {
    union { unsigned u_; float f; } v; v.u_ = (unsigned)u << 16; return v.f;
}

// ---------------- e2[k]: numpy-exact f32 codebook norms ----------------
__global__ __launch_bounds__(64) void k_e2(const float* __restrict__ E,
                                           float* __restrict__ e2) {
    int k = (blockIdx.x << 6) + threadIdx.x;
    const float* row = E + (size_t)k * DD;
    float half[2];
#pragma unroll
    for (int h = 0; h < 2; ++h) {
        const float* a = row + (h << 7);
        float r[8];
#pragma unroll
        for (int j = 0; j < 8; ++j) r[j] = __fmul_rn(a[j], a[j]);
        for (int i = 8; i < 128; i += 8) {
#pragma unroll
            for (int j = 0; j < 8; ++j) {
                float x = a[i + j];
                r[j] = __fadd_rn(r[j], __fmul_rn(x, x));
            }
        }
        half[h] = __fadd_rn(__fadd_rn(__fadd_rn(r[0], r[1]), __fadd_rn(r[2], r[3])),
                            __fadd_rn(__fadd_rn(r[4], r[5]), __fadd_rn(r[6], r[7])));
    }
    e2[k] = __fadd_rn(half[0], half[1]);
}

// ---------------- z2[n]: numpy-exact f32 z-row norms ----------------
__global__ __launch_bounds__(256) void k_z2(const float* __restrict__ Z,
                                            float* __restrict__ z2) {
    int n = (blockIdx.x << 8) + threadIdx.x;
    int b = n >> 10, hw = n & 1023;
    const float* base = Z + (size_t)(b << 8) * HWN + hw;
    float half[2];
#pragma unroll
    for (int h = 0; h < 2; ++h) {
        const float* a = base + (size_t)(h << 7) * HWN;
        float r[8];
#pragma unroll
        for (int j = 0; j < 8; ++j) {
            float x = a[(size_t)j * HWN];
            r[j] = __fmul_rn(x, x);
        }
        for (int i = 8; i < 128; i += 8) {
#pragma unroll
            for (int j = 0; j < 8; ++j) {
                float x = a[(size_t)(i + j) * HWN];
                r[j] = __fadd_rn(r[j], __fmul_rn(x, x));
            }
        }
        half[h] = __fadd_rn(__fadd_rn(__fadd_rn(r[0], r[1]), __fadd_rn(r[2], r[3])),
                            __fadd_rn(__fadd_rn(r[4], r[5]), __fadd_rn(r[6], r[7])));
    }
    z2[n] = __fadd_rn(half[0], half[1]);
}

// ---------------- prep: E -> Eh/El bf16 ----------------
__global__ __launch_bounds__(256) void k_prepE(const float* __restrict__ E,
                                               ushort* __restrict__ Eh,
                                               ushort* __restrict__ El) {
    int i4 = (blockIdx.x << 8) + threadIdx.x;        // 0..65535 float4s
    float4 v = *reinterpret_cast<const float4*>(&E[(size_t)i4 << 2]);
    ushort4 h, l;
    h.x = f2b_rne(v.x); l.x = f2b_rne(v.x - b2f(h.x));
    h.y = f2b_rne(v.y); l.y = f2b_rne(v.y - b2f(h.y));
    h.z = f2b_rne(v.z); l.z = f2b_rne(v.z - b2f(h.z));
    h.w = f2b_rne(v.w); l.w = f2b_rne(v.w - b2f(h.w));
    *reinterpret_cast<ushort4*>(&Eh[(size_t)i4 << 2]) = h;
    *reinterpret_cast<ushort4*>(&El[(size_t)i4 << 2]) = l;
}

// ---------------- prep: Z (NCHW) -> Zh/Zl [n][d] bf16 (transpose) ----------------
__global__ __launch_bounds__(256) void k_prepZ(const float* __restrict__ Z,
                                               ushort* __restrict__ Zh,
                                               ushort* __restrict__ Zl) {
    __shared__ float zc[64][68];       // 17.4 KB
    const int g = blockIdx.x;          // 2048 blocks
    const int b = g >> 6;
    const int rem = g & 63;
    const int d0 = (rem >> 4) << 6;    // 0,64,128,192
    const int hw0 = (rem & 15) << 6;   // 0..960
    const int th = threadIdx.x;

#pragma unroll
    for (int j = 0; j < 16; ++j) {
        int li = (j << 8) + th;        // 0..4095
        int dd = li >> 6;
        int hl = li & 63;
        zc[hl][dd] = Z[(size_t)((b << 8) + d0 + dd) * HWN + hw0 + hl];
    }
    __syncthreads();
#pragma unroll
    for (int s = th; s < 512; s += 256) {
        int hl = s >> 3;
        int dq = (s & 7) << 3;
        ushort hs[8], ls[8];
#pragma unroll
        for (int i = 0; i < 8; ++i) {
            float z = zc[hl][dq + i];
            ushort h = f2b_rne(z);
            hs[i] = h;
            ls[i] = f2b_rne(z - b2f(h));
        }
        size_t addr = (size_t)((b << 10) + hw0 + hl) * DD + d0 + dq;
        *reinterpret_cast<bf16x8*>(&Zh[addr]) = *reinterpret_cast<bf16x8*>(hs);
        *reinterpret_cast<bf16x8*>(&Zl[addr]) = *reinterpret_cast<bf16x8*>(ls);
    }
}

// ------------- MFMA distance pass: 128 rows x 128 codes per block -------------
// split-bf16: dot = zh*eh + zh*el + zl*eh (err ~1e-7 << MARGIN)
__global__ __launch_bounds__(256) void k_dist_mfma(const ushort* __restrict__ Zh,
                                                   const ushort* __restrict__ Zl,
                                                   const ushort* __restrict__ Eh,
                                                   const ushort* __restrict__ El,
                                                   const float* __restrict__ e2,
                                                   float* __restrict__ part) {
    __shared__ ushort zh[128][40], zl[128][40], eh[128][40], el[128][40]; // 40.96 KB
    __shared__ float red[128][2][3];                                     //  3 KB

    const int g = blockIdx.x;          // 2048 = 256 rb x 8 cb
    const int rb = g >> 3, cb = g & 7;
    const int n0 = rb << 7, c0 = cb << 7;
    const int th = threadIdx.x;
    const int wid = th >> 6, lane = th & 63;
    const int wr = wid >> 1, wc = wid & 1;
    const int fr = lane & 15, kg = (lane >> 4) << 3;

    f32x4 acc[4][4];
#pragma unroll
    for (int i = 0; i < 4; ++i)
#pragma unroll
        for (int j = 0; j < 4; ++j) acc[i][j] = (f32x4){0.f, 0.f, 0.f, 0.f};

    for (int kc = 0; kc < 8; ++kc) {
        __syncthreads();               // prev-iter frag reads done
#pragma unroll
        for (int s = th; s < 512; s += 256) {
            int row = s >> 2, c8 = (s & 3) << 3;
            size_t gz = (size_t)(n0 + row) * DD + (kc << 5) + c8;
            *reinterpret_cast<bf16x8*>(&zh[row][c8]) = *reinterpret_cast<const bf16x8*>(&Zh[gz]);
            *reinterpret_cast<bf16x8*>(&zl[row][c8]) = *reinterpret_cast<const bf16x8*>(&Zl[gz]);
            size_t ge = (size_t)(c0 + row) * DD + (kc << 5) + c8;
            *reinterpret_cast<bf16x8*>(&eh[row][c8]) = *reinterpret_cast<const bf16x8*>(&Eh[ge]);
            *reinterpret_cast<bf16x8*>(&el[row][c8]) = *reinterpret_cast<const bf16x8*>(&El[ge]);
        }
        __syncthreads();

        bf16x8 za[4], zb[4], ea[4], eb[4];
#pragma unroll
        for (int mi = 0; mi < 4; ++mi) {
            int r = (wr << 6) + (mi << 4) + fr;
            za[mi] = *reinterpret_cast<bf16x8*>(&zh[r][kg]);
            zb[mi] = *reinterpret_cast<bf16x8*>(&zl[r][kg]);
        }
#pragma unroll
        for (int ni = 0; ni < 4; ++ni) {
            int c = (wc << 6) + (ni << 4) + fr;
            ea[ni] = *reinterpret_cast<bf16x8*>(&eh[c][kg]);
            eb[ni] = *reinterpret_cast<bf16x8*>(&el[c][kg]);
        }
#pragma unroll
        for (int mi = 0; mi < 4; ++mi)
#pragma unroll
            for (int ni = 0; ni < 4; ++ni) {
                acc[mi][ni] = __builtin_amdgcn_mfma_f32_16x16x32_bf16(za[mi], ea[ni], acc[mi][ni], 0, 0, 0);
                acc[mi][ni] = __builtin_amdgcn_mfma_f32_16x16x32_bf16(za[mi], eb[ni], acc[mi][ni], 0, 0, 0);
                acc[mi][ni] = __builtin_amdgcn_mfma_f32_16x16x32_bf16(zb[mi], ea[ni], acc[mi][ni], 0, 0, 0);
            }
    }

    // epilogue: distances + per-row min over this 128-code slice
    float e2v[4];
#pragma unroll
    for (int ni = 0; ni < 4; ++ni) e2v[ni] = e2[c0 + (wc << 6) + (ni << 4) + fr];

    const int rg = lane >> 4;
#pragma unroll
    for (int mi = 0; mi < 4; ++mi) {
#pragma unroll
        for (int j = 0; j < 4; ++j) {
            float m1 = __builtin_inff(), m2 = __builtin_inff(), bi = 3.4e38f;
#pragma unroll
            for (int ni = 0; ni < 4; ++ni) {
                float s = fmaf(-2.f, acc[mi][ni][j], e2v[ni]);
                float c = (float)(c0 + (wc << 6) + (ni << 4) + fr);
                if (s < m1)      { m2 = m1; m1 = s; bi = c; }
                else if (s < m2) { m2 = s; }
            }
#pragma unroll
            for (int m = 1; m <= 8; m <<= 1) {
                float om1 = __shfl_xor(m1, m);
                float om2 = __shfl_xor(m2, m);
                float obi = __shfl_xor(bi, m);
                if (om1 < m1)       { m2 = fminf(m1, om2); m1 = om1; bi = obi; }
                else if (om1 == m1) { bi = fminf(bi, obi); m2 = m1; }
                else                { m2 = fminf(m2, om1); }
            }
            if (fr == 0) {
                int row = (wr << 6) + (mi << 4) + (rg << 2) + j;
                red[row][wc][0] = m1; red[row][wc][1] = m2; red[row][wc][2] = bi;
            }
        }
    }
    __syncthreads();
    if (th < 128) {
        float M1 = red[th][0][0], M2 = red[th][0][1], I = red[th][0][2];
        float v1 = red[th][1][0], v2 = red[th][1][1], vi = red[th][1][2];
        if (v1 < M1)       { M2 = fminf(M1, v2); M1 = v1; I = vi; }
        else if (v1 == M1) { I = fminf(I, vi); M2 = M1; }
        else               { M2 = fminf(M2, v1); }
        size_t p = ((size_t)(n0 + th) * 8 + cb) * 3;
        part[p] = M1; part[p + 1] = M2; part[p + 2] = I;
    }
}

// ---------------- combine 8 code-slices -> bestIdx + flag ----------------
__global__ __launch_bounds__(256) void k_combine(const float* __restrict__ part,
                                                 int* __restrict__ bestIdx) {
    int n = (blockIdx.x << 8) + threadIdx.x;
    const float* p = part + (size_t)n * 24;
    float M1 = __builtin_inff(), M2 = __builtin_inff(), I = 3.4e38f;
    for (int c = 0; c < 8; ++c) {
        float v1 = p[c * 3], v2 = p[c * 3 + 1], vi = p[c * 3 + 2];
        if (v1 < M1)       { M2 = fminf(M1, v2); M1 = v1; I = vi; }
        else if (v1 == M1) { I = fminf(I, vi); M2 = M1; }
        else               { M2 = fminf(M2, v1); }
    }
    int idx = (int)I;
    bestIdx[n] = (M2 - M1 < MARGIN) ? (idx | FLAGBIT) : idx;
}

// ======== fp32 fallback distance pass (round-6, used if ws too small) ========
#define UPD(m1, m2, i1, s, k)                            \
    do {                                                 \
        if ((s) < (m1)) { m2 = m1; m1 = (s); i1 = (k); } \
        else if ((s) < (m2)) { m2 = (s); }               \
    } while (0)

#define FMAJ(j, EV, C)                                   \
    acc[0][j] = fmaf(z4.x, EV.C, acc[0][j]);             \
    acc[1][j] = fmaf(z4.y, EV.C, acc[1][j]);             \
    acc[2][j] = fmaf(z4.z, EV.C, acc[2][j]);             \
    acc[3][j] = fmaf(z4.w, EV.C, acc[3][j]);

#define UROUND(u, C)                                                          \
    {                                                                         \
        float4 z4 = *reinterpret_cast<const float4*>(&zs[dq + u][ty4]);       \
        FMAJ(0, e0, C) FMAJ(1, e1, C) FMAJ(2, e2v, C) FMAJ(3, e3, C)          \
        FMAJ(4, e4, C) FMAJ(5, e5, C) FMAJ(6, e6, C) FMAJ(7, e7, C)           \
    }

__global__ __launch_bounds__(256, 3) void k_dist_f32(const float* __restrict__ Z,
                                                     const float* __restrict__ E,
                                                     const float* __restrict__ e2,
                                                     int* __restrict__ bestIdx) {
    __shared__ float zs[64][68];
    __shared__ float es[128][68];
    const int th = threadIdx.x;
    const int n0 = blockIdx.x << 6;
    const int b = n0 >> 10;
    const int hw0 = n0 & 1023;
    const int tx = th & 15;
    const int ty = th >> 4;
    const int ty4 = ty << 2;
    float m1[4], m2[4];
    int idx[4];
#pragma unroll
    for (int i = 0; i < 4; ++i) { m1[i] = __builtin_inff(); m2[i] = __builtin_inff(); idx[i] = 0; }
    for (int ct = 0; ct < 8; ++ct) {
        float acc[4][8];
#pragma unroll
        for (int i = 0; i < 4; ++i)
#pragma unroll
            for (int j = 0; j < 8; ++j) acc[i][j] = 0.f;
        for (int dc = 0; dc < 4; ++dc) {
            __syncthreads();
#pragma unroll
            for (int j = 0; j < 4; ++j) {
                int i4 = (j << 8) + th;
                int dd = i4 >> 4;
                int rr = (i4 & 15) << 2;
                *reinterpret_cast<float4*>(&zs[dd][rr]) =
                    *reinterpret_cast<const float4*>(
                        &Z[(size_t)((b << 8) + (dc << 6) + dd) * HWN + hw0 + rr]);
            }
#pragma unroll
            for (int j = 0; j < 8; ++j) {
                int i4 = (j << 8) + th;
                int c = i4 >> 4;
                int d4 = (i4 & 15) << 2;
                *reinterpret_cast<float4*>(&es[c][d4]) =
                    *reinterpret_cast<const float4*>(
                        &E[(size_t)((ct << 7) + c) * DD + (dc << 6) + d4]);
            }
            __syncthreads();
#pragma unroll
            for (int dq = 0; dq < 64; dq += 4) {
                float4 e0 = *reinterpret_cast<const float4*>(&es[tx][dq]);
                float4 e1 = *reinterpret_cast<const float4*>(&es[tx + 16][dq]);
                float4 e2v = *reinterpret_cast<const float4*>(&es[tx + 32][dq]);
                float4 e3 = *reinterpret_cast<const float4*>(&es[tx + 48][dq]);
                float4 e4 = *reinterpret_cast<const float4*>(&es[tx + 64][dq]);
                float4 e5 = *reinterpret_cast<const float4*>(&es[tx + 80][dq]);
                float4 e6 = *reinterpret_cast<const float4*>(&es[tx + 96][dq]);
                float4 e7 = *reinterpret_cast<const float4*>(&es[tx + 112][dq]);
                UROUND(0, x)
                UROUND(1, y)
                UROUND(2, z)
                UROUND(3, w)
            }
        }
#pragma unroll
        for (int j = 0; j < 8; ++j) {
            int c = (ct << 7) + tx + (j << 4);
            float en = e2[c];
#pragma unroll
            for (int i = 0; i < 4; ++i) {
                float s = fmaf(-2.f, acc[i][j], en);
                UPD(m1[i], m2[i], idx[i], s, c);
            }
        }
    }
    __syncthreads();
    float* red = &es[0][0];
#pragma unroll
    for (int i = 0; i < 4; ++i) {
        int r = ty4 + i;
        int base = ((r << 4) + tx) * 3;
        red[base] = m1[i]; red[base + 1] = m2[i]; red[base + 2] = (float)idx[i];
    }
    __syncthreads();
    if (th < 64) {
        float M1 = __builtin_inff(), M2 = __builtin_inff(), I = 3.4e38f;
        for (int t = 0; t < 16; ++t) {
            int base = ((th << 4) + t) * 3;
            float v1 = red[base], v2 = red[base + 1], vi = red[base + 2];
            if (v1 < M1)       { M2 = fminf(M1, v2); M1 = v1; I = vi; }
            else if (v1 == M1) { I = fminf(I, vi); M2 = fminf(M2, v1); M2 = fminf(M2, v2); }
            else               { M2 = fminf(M2, v1); }
        }
        int id = (int)I;
        bestIdx[n0 + th] = (M2 - M1 < MARGIN) ? (id | FLAGBIT) : id;
    }
}

// -------- np-f32-emulating re-argmin for flagged rows --------
__global__ __launch_bounds__(64) void k_refine(const float* __restrict__ Z,
                                               const float* __restrict__ E,
                                               const float* __restrict__ e2,
                                               const float* __restrict__ z2,
                                               int* __restrict__ bestIdx) {
    __shared__ float zr[DD];
    const int l = threadIdx.x;
    for (int i = 0; i < 16; ++i) {
        int n = (blockIdx.x << 4) + i;
        if (!(bestIdx[n] & FLAGBIT)) continue;
        int b = n >> 10, hw = n & 1023;
        __syncthreads();
#pragma unroll
        for (int j = 0; j < 4; ++j)
            zr[(l << 2) + j] = Z[(size_t)((b << 8) + (l << 2) + j) * HWN + hw];
        __syncthreads();
        const float z2v = z2[n];
        float gbest = __builtin_inff();
        int bi = KK;
        for (int kk = 0; kk < 16; ++kk) {
            int k = (kk << 6) + l;
            double dot = 0.0;
            for (int d = 0; d < DD; d += 4) {
                float4 e4 = *reinterpret_cast<const float4*>(&E[(size_t)k * DD + d]);
                dot += (double)e4.x * zr[d]     + (double)e4.y * zr[d + 1]
                     + (double)e4.z * zr[d + 2] + (double)e4.w * zr[d + 3];
            }
            float c = (float)dot;
            float t = __fmul_rn(2.0f, c);
            float gg = __fsub_rn(__fadd_rn(z2v, e2[k]), t);
            if (gg < gbest) { gbest = gg; bi = k; }
        }
#pragma unroll
        for (int off = 32; off > 0; off >>= 1) {
            float og = __shfl_down(gbest, off);
            int oi = __shfl_down(bi, off);
            if (og < gbest || (og == gbest && oi < bi)) { gbest = og; bi = oi; }
        }
        if (l == 0) bestIdx[n] = bi;
    }
}

// -------- outputs: idx, loss (NHWC), z_q (NCHW) --------
__global__ __launch_bounds__(256) void k_out(const float* __restrict__ Z,
                                             const float* __restrict__ E,
                                             const int* __restrict__ bestIdx,
                                             float* __restrict__ out) {
    __shared__ float zc[64][68];
    __shared__ int idxs[64];
    const int th = threadIdx.x;
    const int n0 = blockIdx.x << 6;
    const int b = n0 >> 10;
    const int hw0 = n0 & 1023;

    if (th < 64) {
        int id = bestIdx[n0 + th] & 1023;
        idxs[th] = id;
        out[IDX_OFF + n0 + th] = (float)id;
    }
    __syncthreads();

    for (int dc = 0; dc < 4; ++dc) {
        __syncthreads();
#pragma unroll
        for (int j = 0; j < 16; ++j) {
            int li = (j << 8) + th;
            int dd = li >> 6;
            int r = li & 63;
            zc[r][dd] = Z[(size_t)((b << 8) + (dc << 6) + dd) * HWN + hw0 + r];
        }
        __syncthreads();
#pragma unroll
        for (int j = 0; j < 4; ++j) {
            int i4 = (j << 8) + th;
            int r = i4 >> 4;
            int f = (i4 & 15) << 2;
            float4 e4 = *reinterpret_cast<const float4*>(
                &E[(size_t)idxs[r] * DD + (dc << 6) + f]);
            float4 z4 = *reinterpret_cast<const float4*>(&zc[r][f]);
            float4 o;
            o.x = (e4.x - z4.x) * (e4.x - z4.x);
            o.y = (e4.y - z4.y) * (e4.y - z4.y);
            o.z = (e4.z - z4.z) * (e4.z - z4.z);
            o.w = (e4.w - z4.w) * (e4.w - z4.w);
            *reinterpret_cast<float4*>(
                &out[LOSS_OFF + (size_t)(n0 + r) * DD + (dc << 6) + f]) = o;
        }
#pragma unroll
        for (int j = 0; j < 16; ++j) {
            int li = (j << 8) + th;
            int dd = li >> 6;
            int r = li & 63;
            out[ZQ_OFF + (size_t)((b << 8) + (dc << 6) + dd) * HWN + hw0 + r] =
                E[(size_t)idxs[r] * DD + (dc << 6) + dd];
        }
    }
}

extern "C" void kernel_launch(void* const* d_in, const int* in_sizes, int n_in,
                              void* d_out, int out_size, void* d_ws, size_t ws_size,
                              hipStream_t stream) {
    const float* Z = (const float*)d_in[0];           // [32,256,32,32] f32
    const float* E = (const float*)d_in[1];           // [1024,256] f32
    float* out = (float*)d_out;
    char* ws = (char*)d_ws;
    float* e2 = (float*)ws;
    float* z2 = (float*)(ws + 4096);
    int* bestIdx = (int*)(ws + 135168);

    k_e2<<<KK / 64, 64, 0, stream>>>(E, e2);
    k_z2<<<NN / 256, 256, 0, stream>>>(Z, z2);

    if (ws_size >= WS_NEED) {
        float* part = (float*)(ws + 266240);
        ushort* Eh = (ushort*)(ws + 3411968);
        ushort* El = (ushort*)(ws + 3936256);
        ushort* Zh = (ushort*)(ws + 4460544);
        ushort* Zl = (ushort*)(ws + 21237760);
        k_prepE<<<256, 256, 0, stream>>>(E, Eh, El);
        k_prepZ<<<2048, 256, 0, stream>>>(Z, Zh, Zl);
        k_dist_mfma<<<2048, 256, 0, stream>>>(Zh, Zl, Eh, El, e2, part);
        k_combine<<<NN / 256, 256, 0, stream>>>(part, bestIdx);
    } else {
        k_dist_f32<<<NN / 64, 256, 0, stream>>>(Z, E, e2, bestIdx);
    }

    k_refine<<<NN / 16, 64, 0, stream>>>(Z, E, e2, z2, bestIdx);
    k_out<<<NN / 64, 256, 0, stream>>>(Z, E, bestIdx, out);
}

// Round 8
// 276.044 us; speedup vs baseline: 2.3929x; 1.5357x over previous
//
#include <hip/hip_runtime.h>

#define DD 256
#define HWN 1024
#define NN 32768
#define KK 1024
#define MARGIN 1e-4f
#define FLAGBIT (1 << 30)

// f32-element offsets into d_out (out_size = 16809984 floats):
#define ZQ_OFF   0          // z_q   [32,256,32,32]
#define IDX_OFF  8388608    // idx   [32768]
#define LOSS_OFF 8421376    // loss  [32,32,32,256] (NHWC)

// ws layout (MFMA path needs WS_NEED bytes; else fp32 fallback):
// [0, 4096)            float e2[1024]
// [4096, 135168)       float z2[32768]
// [135168, 266240)     int   bestIdx[32768]
// [266240, 3411968)    float part[32768][8][3]
// [3411968, 3936256)   ushort Eh[1024][256]
// [3936256, 4460544)   ushort El[1024][256]
// [4460544, 21237760)  ushort Zh[32768][256]
// [21237760, 38014976) ushort Zl[32768][256]
// [38014976, 38015040) int flagCount
// [38015040, 38146112) int flagList[32768]
#define WS_NEED 38146112

typedef __attribute__((ext_vector_type(8))) short bf16x8;
typedef __attribute__((ext_vector_type(4))) float f32x4;

__device__ __forceinline__ ushort f2b_rne(float x) {
    union { float f; unsigned u; } v; v.f = x;
    unsigned r = v.u + 0x7fffu + ((v.u >> 16) & 1u);
    return (ushort)(r >> 16);
}
__device__ __forceinline__ float b2f(ushort u) {
    union { unsigned u_; float f; } v; v.u_ = (unsigned)u << 16; return v.f;
}

// ---------------- e2[k]: numpy-exact f32 codebook norms ----------------
__global__ __launch_bounds__(64) void k_e2(const float* __restrict__ E,
                                           float* __restrict__ e2) {
    int k = (blockIdx.x << 6) + threadIdx.x;
    const float* row = E + (size_t)k * DD;
    float half[2];
#pragma unroll
    for (int h = 0; h < 2; ++h) {
        const float* a = row + (h << 7);
        float r[8];
#pragma unroll
        for (int j = 0; j < 8; ++j) r[j] = __fmul_rn(a[j], a[j]);
        for (int i = 8; i < 128; i += 8) {
#pragma unroll
            for (int j = 0; j < 8; ++j) {
                float x = a[i + j];
                r[j] = __fadd_rn(r[j], __fmul_rn(x, x));
            }
        }
        half[h] = __fadd_rn(__fadd_rn(__fadd_rn(r[0], r[1]), __fadd_rn(r[2], r[3])),
                            __fadd_rn(__fadd_rn(r[4], r[5]), __fadd_rn(r[6], r[7])));
    }
    e2[k] = __fadd_rn(half[0], half[1]);
}

// ---------------- z2[n]: numpy-exact f32 z-row norms ----------------
__global__ __launch_bounds__(256) void k_z2(const float* __restrict__ Z,
                                            float* __restrict__ z2) {
    int n = (blockIdx.x << 8) + threadIdx.x;
    int b = n >> 10, hw = n & 1023;
    const float* base = Z + (size_t)(b << 8) * HWN + hw;
    float half[2];
#pragma unroll
    for (int h = 0; h < 2; ++h) {
        const float* a = base + (size_t)(h << 7) * HWN;
        float r[8];
#pragma unroll
        for (int j = 0; j < 8; ++j) {
            float x = a[(size_t)j * HWN];
            r[j] = __fmul_rn(x, x);
        }
        for (int i = 8; i < 128; i += 8) {
#pragma unroll
            for (int j = 0; j < 8; ++j) {
                float x = a[(size_t)(i + j) * HWN];
                r[j] = __fadd_rn(r[j], __fmul_rn(x, x));
            }
        }
        half[h] = __fadd_rn(__fadd_rn(__fadd_rn(r[0], r[1]), __fadd_rn(r[2], r[3])),
                            __fadd_rn(__fadd_rn(r[4], r[5]), __fadd_rn(r[6], r[7])));
    }
    z2[n] = __fadd_rn(half[0], half[1]);
}

// ---------------- prep: E -> Eh/El bf16 (+ zero flag counter) ----------------
__global__ __launch_bounds__(256) void k_prepE(const float* __restrict__ E,
                                               ushort* __restrict__ Eh,
                                               ushort* __restrict__ El,
                                               int* __restrict__ flagCount) {
    if (blockIdx.x == 0 && threadIdx.x == 0) *flagCount = 0;
    int i4 = (blockIdx.x << 8) + threadIdx.x;        // 0..65535 float4s
    float4 v = *reinterpret_cast<const float4*>(&E[(size_t)i4 << 2]);
    ushort4 h, l;
    h.x = f2b_rne(v.x); l.x = f2b_rne(v.x - b2f(h.x));
    h.y = f2b_rne(v.y); l.y = f2b_rne(v.y - b2f(h.y));
    h.z = f2b_rne(v.z); l.z = f2b_rne(v.z - b2f(h.z));
    h.w = f2b_rne(v.w); l.w = f2b_rne(v.w - b2f(h.w));
    *reinterpret_cast<ushort4*>(&Eh[(size_t)i4 << 2]) = h;
    *reinterpret_cast<ushort4*>(&El[(size_t)i4 << 2]) = l;
}

// ---------------- prep: Z (NCHW) -> Zh/Zl [n][d] bf16 (transpose) ----------------
__global__ __launch_bounds__(256) void k_prepZ(const float* __restrict__ Z,
                                               ushort* __restrict__ Zh,
                                               ushort* __restrict__ Zl) {
    __shared__ float zc[64][68];       // 17.4 KB
    const int g = blockIdx.x;          // 2048 blocks
    const int b = g >> 6;
    const int rem = g & 63;
    const int d0 = (rem >> 4) << 6;    // 0,64,128,192
    const int hw0 = (rem & 15) << 6;   // 0..960
    const int th = threadIdx.x;

#pragma unroll
    for (int j = 0; j < 16; ++j) {
        int li = (j << 8) + th;        // 0..4095
        int dd = li >> 6;
        int hl = li & 63;
        zc[hl][dd] = Z[(size_t)((b << 8) + d0 + dd) * HWN + hw0 + hl];
    }
    __syncthreads();
#pragma unroll
    for (int s = th; s < 512; s += 256) {
        int hl = s >> 3;
        int dq = (s & 7) << 3;
        ushort hs[8], ls[8];
#pragma unroll
        for (int i = 0; i < 8; ++i) {
            float z = zc[hl][dq + i];
            ushort h = f2b_rne(z);
            hs[i] = h;
            ls[i] = f2b_rne(z - b2f(h));
        }
        size_t addr = (size_t)((b << 10) + hw0 + hl) * DD + d0 + dq;
        *reinterpret_cast<bf16x8*>(&Zh[addr]) = *reinterpret_cast<bf16x8*>(hs);
        *reinterpret_cast<bf16x8*>(&Zl[addr]) = *reinterpret_cast<bf16x8*>(ls);
    }
}

// ------------- MFMA distance pass: 128 rows x 128 codes per block -------------
__global__ __launch_bounds__(256) void k_dist_mfma(const ushort* __restrict__ Zh,
                                                   const ushort* __restrict__ Zl,
                                                   const ushort* __restrict__ Eh,
                                                   const ushort* __restrict__ El,
                                                   const float* __restrict__ e2,
                                                   float* __restrict__ part) {
    __shared__ ushort zh[128][40], zl[128][40], eh[128][40], el[128][40]; // 40.96 KB
    __shared__ float red[128][2][3];                                     //  3 KB

    const int g = blockIdx.x;          // 2048 = 256 rb x 8 cb
    const int rb = g >> 3, cb = g & 7;
    const int n0 = rb << 7, c0 = cb << 7;
    const int th = threadIdx.x;
    const int wid = th >> 6, lane = th & 63;
    const int wr = wid >> 1, wc = wid & 1;
    const int fr = lane & 15, kg = (lane >> 4) << 3;

    f32x4 acc[4][4];
#pragma unroll
    for (int i = 0; i < 4; ++i)
#pragma unroll
        for (int j = 0; j < 4; ++j) acc[i][j] = (f32x4){0.f, 0.f, 0.f, 0.f};

    for (int kc = 0; kc < 8; ++kc) {
        __syncthreads();
#pragma unroll
        for (int s = th; s < 512; s += 256) {
            int row = s >> 2, c8 = (s & 3) << 3;
            size_t gz = (size_t)(n0 + row) * DD + (kc << 5) + c8;
            *reinterpret_cast<bf16x8*>(&zh[row][c8]) = *reinterpret_cast<const bf16x8*>(&Zh[gz]);
            *reinterpret_cast<bf16x8*>(&zl[row][c8]) = *reinterpret_cast<const bf16x8*>(&Zl[gz]);
            size_t ge = (size_t)(c0 + row) * DD + (kc << 5) + c8;
            *reinterpret_cast<bf16x8*>(&eh[row][c8]) = *reinterpret_cast<const bf16x8*>(&Eh[ge]);
            *reinterpret_cast<bf16x8*>(&el[row][c8]) = *reinterpret_cast<const bf16x8*>(&El[ge]);
        }
        __syncthreads();

        bf16x8 za[4], zb[4], ea[4], eb[4];
#pragma unroll
        for (int mi = 0; mi < 4; ++mi) {
            int r = (wr << 6) + (mi << 4) + fr;
            za[mi] = *reinterpret_cast<bf16x8*>(&zh[r][kg]);
            zb[mi] = *reinterpret_cast<bf16x8*>(&zl[r][kg]);
        }
#pragma unroll
        for (int ni = 0; ni < 4; ++ni) {
            int c = (wc << 6) + (ni << 4) + fr;
            ea[ni] = *reinterpret_cast<bf16x8*>(&eh[c][kg]);
            eb[ni] = *reinterpret_cast<bf16x8*>(&el[c][kg]);
        }
#pragma unroll
        for (int mi = 0; mi < 4; ++mi)
#pragma unroll
            for (int ni = 0; ni < 4; ++ni) {
                acc[mi][ni] = __builtin_amdgcn_mfma_f32_16x16x32_bf16(za[mi], ea[ni], acc[mi][ni], 0, 0, 0);
                acc[mi][ni] = __builtin_amdgcn_mfma_f32_16x16x32_bf16(za[mi], eb[ni], acc[mi][ni], 0, 0, 0);
                acc[mi][ni] = __builtin_amdgcn_mfma_f32_16x16x32_bf16(zb[mi], ea[ni], acc[mi][ni], 0, 0, 0);
            }
    }

    float e2v[4];
#pragma unroll
    for (int ni = 0; ni < 4; ++ni) e2v[ni] = e2[c0 + (wc << 6) + (ni << 4) + fr];

    const int rg = lane >> 4;
#pragma unroll
    for (int mi = 0; mi < 4; ++mi) {
#pragma unroll
        for (int j = 0; j < 4; ++j) {
            float m1 = __builtin_inff(), m2 = __builtin_inff(), bi = 3.4e38f;
#pragma unroll
            for (int ni = 0; ni < 4; ++ni) {
                float s = fmaf(-2.f, acc[mi][ni][j], e2v[ni]);
                float c = (float)(c0 + (wc << 6) + (ni << 4) + fr);
                if (s < m1)      { m2 = m1; m1 = s; bi = c; }
                else if (s < m2) { m2 = s; }
            }
#pragma unroll
            for (int m = 1; m <= 8; m <<= 1) {
                float om1 = __shfl_xor(m1, m);
                float om2 = __shfl_xor(m2, m);
                float obi = __shfl_xor(bi, m);
                if (om1 < m1)       { m2 = fminf(m1, om2); m1 = om1; bi = obi; }
                else if (om1 == m1) { bi = fminf(bi, obi); m2 = m1; }
                else                { m2 = fminf(m2, om1); }
            }
            if (fr == 0) {
                int row = (wr << 6) + (mi << 4) + (rg << 2) + j;
                red[row][wc][0] = m1; red[row][wc][1] = m2; red[row][wc][2] = bi;
            }
        }
    }
    __syncthreads();
    if (th < 128) {
        float M1 = red[th][0][0], M2 = red[th][0][1], I = red[th][0][2];
        float v1 = red[th][1][0], v2 = red[th][1][1], vi = red[th][1][2];
        if (v1 < M1)       { M2 = fminf(M1, v2); M1 = v1; I = vi; }
        else if (v1 == M1) { I = fminf(I, vi); M2 = M1; }
        else               { M2 = fminf(M2, v1); }
        size_t p = ((size_t)(n0 + th) * 8 + cb) * 3;
        part[p] = M1; part[p + 1] = M2; part[p + 2] = I;
    }
}

// ------- combine 8 code-slices -> bestIdx + compacted near-tie list -------
__global__ __launch_bounds__(256) void k_combine(const float* __restrict__ part,
                                                 int* __restrict__ bestIdx,
                                                 int* __restrict__ flagList,
                                                 int* __restrict__ flagCount) {
    int n = (blockIdx.x << 8) + threadIdx.x;
    const float* p = part + (size_t)n * 24;
    float M1 = __builtin_inff(), M2 = __builtin_inff(), I = 3.4e38f;
    for (int c = 0; c < 8; ++c) {
        float v1 = p[c * 3], v2 = p[c * 3 + 1], vi = p[c * 3 + 2];
        if (v1 < M1)       { M2 = fminf(M1, v2); M1 = v1; I = vi; }
        else if (v1 == M1) { I = fminf(I, vi); M2 = M1; }
        else               { M2 = fminf(M2, v1); }
    }
    bestIdx[n] = (int)I;
    if (M2 - M1 < MARGIN) {
        int pos = atomicAdd(flagCount, 1);
        flagList[pos] = n;
    }
}

// -- compacted np-f32-grid re-argmin: one wave per flagged row, 4-way f64 ILP --
__global__ __launch_bounds__(64) void k_refine_c(const float* __restrict__ Z,
                                                 const float* __restrict__ E,
                                                 const float* __restrict__ e2,
                                                 const float* __restrict__ z2,
                                                 int* __restrict__ bestIdx,
                                                 const int* __restrict__ flagList,
                                                 const int* __restrict__ flagCount) {
    __shared__ float zr[DD];
    const int l = threadIdx.x;
    const int cnt = *flagCount;
    for (int i = blockIdx.x; i < cnt; i += (int)gridDim.x) {
        int n = flagList[i];
        int b = n >> 10, hw = n & 1023;
        __syncthreads();
#pragma unroll
        for (int j = 0; j < 4; ++j)
            zr[(l << 2) + j] = Z[(size_t)((b << 8) + (l << 2) + j) * HWN + hw];
        __syncthreads();
        const float z2v = z2[n];
        float gbest = __builtin_inff();
        int bi = KK;
        for (int kk = 0; kk < 16; ++kk) {
            int k = (kk << 6) + l;               // ascending per lane
            const float* er = &E[(size_t)k * DD];
            double s0 = 0.0, s1 = 0.0, s2 = 0.0, s3 = 0.0;
#pragma unroll 4
            for (int d = 0; d < DD; d += 16) {
                float4 a = *reinterpret_cast<const float4*>(&er[d]);
                float4 b4 = *reinterpret_cast<const float4*>(&er[d + 4]);
                float4 c4 = *reinterpret_cast<const float4*>(&er[d + 8]);
                float4 e4 = *reinterpret_cast<const float4*>(&er[d + 12]);
                s0 += (double)a.x * zr[d]      + (double)a.y * zr[d + 1]
                    + (double)a.z * zr[d + 2]  + (double)a.w * zr[d + 3];
                s1 += (double)b4.x * zr[d + 4] + (double)b4.y * zr[d + 5]
                    + (double)b4.z * zr[d + 6] + (double)b4.w * zr[d + 7];
                s2 += (double)c4.x * zr[d + 8] + (double)c4.y * zr[d + 9]
                    + (double)c4.z * zr[d + 10]+ (double)c4.w * zr[d + 11];
                s3 += (double)e4.x * zr[d + 12]+ (double)e4.y * zr[d + 13]
                    + (double)e4.z * zr[d + 14]+ (double)e4.w * zr[d + 15];
            }
            double dot = (s0 + s1) + (s2 + s3);
            float c = (float)dot;                // np's f32 cross (to sgemm noise)
            float t = __fmul_rn(2.0f, c);
            float g = __fsub_rn(__fadd_rn(z2v, e2[k]), t);
            if (g < gbest) { gbest = g; bi = k; }
        }
#pragma unroll
        for (int off = 32; off > 0; off >>= 1) {
            float og = __shfl_down(gbest, off);
            int oi = __shfl_down(bi, off);
            if (og < gbest || (og == gbest && oi < bi)) { gbest = og; bi = oi; }
        }
        if (l == 0) bestIdx[n] = bi;
    }
}

// ======== fp32 fallback distance pass (used if ws too small) ========
#define UPD(m1, m2, i1, s, k)                            \
    do {                                                 \
        if ((s) < (m1)) { m2 = m1; m1 = (s); i1 = (k); } \
        else if ((s) < (m2)) { m2 = (s); }               \
    } while (0)

#define FMAJ(j, EV, C)                                   \
    acc[0][j] = fmaf(z4.x, EV.C, acc[0][j]);             \
    acc[1][j] = fmaf(z4.y, EV.C, acc[1][j]);             \
    acc[2][j] = fmaf(z4.z, EV.C, acc[2][j]);             \
    acc[3][j] = fmaf(z4.w, EV.C, acc[3][j]);

#define UROUND(u, C)                                                          \
    {                                                                         \
        float4 z4 = *reinterpret_cast<const float4*>(&zs[dq + u][ty4]);       \
        FMAJ(0, e0, C) FMAJ(1, e1, C) FMAJ(2, e2v, C) FMAJ(3, e3, C)          \
        FMAJ(4, e4, C) FMAJ(5, e5, C) FMAJ(6, e6, C) FMAJ(7, e7, C)           \
    }

__global__ __launch_bounds__(256, 3) void k_dist_f32(const float* __restrict__ Z,
                                                     const float* __restrict__ E,
                                                     const float* __restrict__ e2,
                                                     int* __restrict__ bestIdx) {
    __shared__ float zs[64][68];
    __shared__ float es[128][68];
    const int th = threadIdx.x;
    const int n0 = blockIdx.x << 6;
    const int b = n0 >> 10;
    const int hw0 = n0 & 1023;
    const int tx = th & 15;
    const int ty = th >> 4;
    const int ty4 = ty << 2;
    float m1[4], m2[4];
    int idx[4];
#pragma unroll
    for (int i = 0; i < 4; ++i) { m1[i] = __builtin_inff(); m2[i] = __builtin_inff(); idx[i] = 0; }
    for (int ct = 0; ct < 8; ++ct) {
        float acc[4][8];
#pragma unroll
        for (int i = 0; i < 4; ++i)
#pragma unroll
            for (int j = 0; j < 8; ++j) acc[i][j] = 0.f;
        for (int dc = 0; dc < 4; ++dc) {
            __syncthreads();
#pragma unroll
            for (int j = 0; j < 4; ++j) {
                int i4 = (j << 8) + th;
                int dd = i4 >> 4;
                int rr = (i4 & 15) << 2;
                *reinterpret_cast<float4*>(&zs[dd][rr]) =
                    *reinterpret_cast<const float4*>(
                        &Z[(size_t)((b << 8) + (dc << 6) + dd) * HWN + hw0 + rr]);
            }
#pragma unroll
            for (int j = 0; j < 8; ++j) {
                int i4 = (j << 8) + th;
                int c = i4 >> 4;
                int d4 = (i4 & 15) << 2;
                *reinterpret_cast<float4*>(&es[c][d4]) =
                    *reinterpret_cast<const float4*>(
                        &E[(size_t)((ct << 7) + c) * DD + (dc << 6) + d4]);
            }
            __syncthreads();
#pragma unroll
            for (int dq = 0; dq < 64; dq += 4) {
                float4 e0 = *reinterpret_cast<const float4*>(&es[tx][dq]);
                float4 e1 = *reinterpret_cast<const float4*>(&es[tx + 16][dq]);
                float4 e2v = *reinterpret_cast<const float4*>(&es[tx + 32][dq]);
                float4 e3 = *reinterpret_cast<const float4*>(&es[tx + 48][dq]);
                float4 e4 = *reinterpret_cast<const float4*>(&es[tx + 64][dq]);
                float4 e5 = *reinterpret_cast<const float4*>(&es[tx + 80][dq]);
                float4 e6 = *reinterpret_cast<const float4*>(&es[tx + 96][dq]);
                float4 e7 = *reinterpret_cast<const float4*>(&es[tx + 112][dq]);
                UROUND(0, x)
                UROUND(1, y)
                UROUND(2, z)
                UROUND(3, w)
            }
        }
#pragma unroll
        for (int j = 0; j < 8; ++j) {
            int c = (ct << 7) + tx + (j << 4);
            float en = e2[c];
#pragma unroll
            for (int i = 0; i < 4; ++i) {
                float s = fmaf(-2.f, acc[i][j], en);
                UPD(m1[i], m2[i], idx[i], s, c);
            }
        }
    }
    __syncthreads();
    float* red = &es[0][0];
#pragma unroll
    for (int i = 0; i < 4; ++i) {
        int r = ty4 + i;
        int base = ((r << 4) + tx) * 3;
        red[base] = m1[i]; red[base + 1] = m2[i]; red[base + 2] = (float)idx[i];
    }
    __syncthreads();
    if (th < 64) {
        float M1 = __builtin_inff(), M2 = __builtin_inff(), I = 3.4e38f;
        for (int t = 0; t < 16; ++t) {
            int base = ((th << 4) + t) * 3;
            float v1 = red[base], v2 = red[base + 1], vi = red[base + 2];
            if (v1 < M1)       { M2 = fminf(M1, v2); M1 = v1; I = vi; }
            else if (v1 == M1) { I = fminf(I, vi); M2 = fminf(M2, v1); M2 = fminf(M2, v2); }
            else               { M2 = fminf(M2, v1); }
        }
        int id = (int)I;
        bestIdx[n0 + th] = (M2 - M1 < MARGIN) ? (id | FLAGBIT) : id;
    }
}

// -------- fallback-path refine (FLAGBIT scan, unchanged semantics) --------
__global__ __launch_bounds__(64) void k_refine(const float* __restrict__ Z,
                                               const float* __restrict__ E,
                                               const float* __restrict__ e2,
                                               const float* __restrict__ z2,
                                               int* __restrict__ bestIdx) {
    __shared__ float zr[DD];
    const int l = threadIdx.x;
    for (int i = 0; i < 16; ++i) {
        int n = (blockIdx.x << 4) + i;
        if (!(bestIdx[n] & FLAGBIT)) continue;
        int b = n >> 10, hw = n & 1023;
        __syncthreads();
#pragma unroll
        for (int j = 0; j < 4; ++j)
            zr[(l << 2) + j] = Z[(size_t)((b << 8) + (l << 2) + j) * HWN + hw];
        __syncthreads();
        const float z2v = z2[n];
        float gbest = __builtin_inff();
        int bi = KK;
        for (int kk = 0; kk < 16; ++kk) {
            int k = (kk << 6) + l;
            double dot = 0.0;
            for (int d = 0; d < DD; d += 4) {
                float4 e4 = *reinterpret_cast<const float4*>(&E[(size_t)k * DD + d]);
                dot += (double)e4.x * zr[d]     + (double)e4.y * zr[d + 1]
                     + (double)e4.z * zr[d + 2] + (double)e4.w * zr[d + 3];
            }
            float c = (float)dot;
            float t = __fmul_rn(2.0f, c);
            float gg = __fsub_rn(__fadd_rn(z2v, e2[k]), t);
            if (gg < gbest) { gbest = gg; bi = k; }
        }
#pragma unroll
        for (int off = 32; off > 0; off >>= 1) {
            float og = __shfl_down(gbest, off);
            int oi = __shfl_down(bi, off);
            if (og < gbest || (og == gbest && oi < bi)) { gbest = og; bi = oi; }
        }
        if (l == 0) bestIdx[n] = bi;
    }
}

// -------- outputs: idx, loss (NHWC), z_q (NCHW) --------
__global__ __launch_bounds__(256) void k_out(const float* __restrict__ Z,
                                             const float* __restrict__ E,
                                             const int* __restrict__ bestIdx,
                                             float* __restrict__ out) {
    __shared__ float zc[64][68];
    __shared__ int idxs[64];
    const int th = threadIdx.x;
    const int n0 = blockIdx.x << 6;
    const int b = n0 >> 10;
    const int hw0 = n0 & 1023;

    if (th < 64) {
        int id = bestIdx[n0 + th] & 1023;
        idxs[th] = id;
        out[IDX_OFF + n0 + th] = (float)id;
    }
    __syncthreads();

    for (int dc = 0; dc < 4; ++dc) {
        __syncthreads();
#pragma unroll
        for (int j = 0; j < 16; ++j) {
            int li = (j << 8) + th;
            int dd = li >> 6;
            int r = li & 63;
            zc[r][dd] = Z[(size_t)((b << 8) + (dc << 6) + dd) * HWN + hw0 + r];
        }
        __syncthreads();
#pragma unroll
        for (int j = 0; j < 4; ++j) {
            int i4 = (j << 8) + th;
            int r = i4 >> 4;
            int f = (i4 & 15) << 2;
            float4 e4 = *reinterpret_cast<const float4*>(
                &E[(size_t)idxs[r] * DD + (dc << 6) + f]);
            float4 z4 = *reinterpret_cast<const float4*>(&zc[r][f]);
            float4 o;
            o.x = (e4.x - z4.x) * (e4.x - z4.x);
            o.y = (e4.y - z4.y) * (e4.y - z4.y);
            o.z = (e4.z - z4.z) * (e4.z - z4.z);
            o.w = (e4.w - z4.w) * (e4.w - z4.w);
            *reinterpret_cast<float4*>(
                &out[LOSS_OFF + (size_t)(n0 + r) * DD + (dc << 6) + f]) = o;
        }
#pragma unroll
        for (int j = 0; j < 16; ++j) {
            int li = (j << 8) + th;
            int dd = li >> 6;
            int r = li & 63;
            out[ZQ_OFF + (size_t)((b << 8) + (dc << 6) + dd) * HWN + hw0 + r] =
                E[(size_t)idxs[r] * DD + (dc << 6) + dd];
        }
    }
}

extern "C" void kernel_launch(void* const* d_in, const int* in_sizes, int n_in,
                              void* d_out, int out_size, void* d_ws, size_t ws_size,
                              hipStream_t stream) {
    const float* Z = (const float*)d_in[0];           // [32,256,32,32] f32
    const float* E = (const float*)d_in[1];           // [1024,256] f32
    float* out = (float*)d_out;
    char* ws = (char*)d_ws;
    float* e2 = (float*)ws;
    float* z2 = (float*)(ws + 4096);
    int* bestIdx = (int*)(ws + 135168);

    k_e2<<<KK / 64, 64, 0, stream>>>(E, e2);
    k_z2<<<NN / 256, 256, 0, stream>>>(Z, z2);

    if (ws_size >= WS_NEED) {
        float* part = (float*)(ws + 266240);
        ushort* Eh = (ushort*)(ws + 3411968);
        ushort* El = (ushort*)(ws + 3936256);
        ushort* Zh = (ushort*)(ws + 4460544);
        ushort* Zl = (ushort*)(ws + 21237760);
        int* flagCount = (int*)(ws + 38014976);
        int* flagList = (int*)(ws + 38015040);
        k_prepE<<<256, 256, 0, stream>>>(E, Eh, El, flagCount);
        k_prepZ<<<2048, 256, 0, stream>>>(Z, Zh, Zl);
        k_dist_mfma<<<2048, 256, 0, stream>>>(Zh, Zl, Eh, El, e2, part);
        k_combine<<<NN / 256, 256, 0, stream>>>(part, bestIdx, flagList, flagCount);
        k_refine_c<<<4096, 64, 0, stream>>>(Z, E, e2, z2, bestIdx, flagList, flagCount);
    } else {
        k_dist_f32<<<NN / 64, 256, 0, stream>>>(Z, E, e2, bestIdx);
        k_refine<<<NN / 16, 64, 0, stream>>>(Z, E, e2, z2, bestIdx);
    }

    k_out<<<NN / 64, 256, 0, stream>>>(Z, E, bestIdx, out);
}